// Round 5
// baseline (442.742 us; speedup 1.0000x reference)
//
#include <hip/hip_runtime.h>

// ---------- types ----------
typedef __bf16 bf16x8 __attribute__((ext_vector_type(8)));
typedef float f32x4 __attribute__((ext_vector_type(4)));
typedef float f32x16 __attribute__((ext_vector_type(16)));
typedef unsigned short u16x8 __attribute__((ext_vector_type(8)));
typedef unsigned u32x2 __attribute__((ext_vector_type(2)));
typedef unsigned u32x4 __attribute__((ext_vector_type(4)));

__device__ __forceinline__ unsigned short f2bf(float f) {
  union { float f; unsigned u; } v; v.f = f;
  unsigned r = (v.u + 0x7fffu + ((v.u >> 16) & 1u)) >> 16;
  return (unsigned short)r;
}
__device__ __forceinline__ float bf2f(unsigned short s) {
  union { unsigned u; float f; } v; v.u = ((unsigned)s) << 16;
  return v.f;
}

#define GLD16(g, l)                                                        \
  __builtin_amdgcn_global_load_lds(                                        \
      (const __attribute__((address_space(1))) void*)(g),                  \
      (__attribute__((address_space(3))) void*)(l), 16, 0, 0)

// XOR swizzle for 64-element (128B) rows.
__device__ __forceinline__ int swzc(int row, int colel) {
  return colel ^ ((((row & 7) ^ ((row >> 3) & 7)) & 7) << 3);
}

__device__ __forceinline__ u32x2 plswap(unsigned a, unsigned b) {
  return __builtin_amdgcn_permlane32_swap(a, b, false, false);
}
__device__ __forceinline__ float pair_max(float x) {
  u32x2 r = plswap(__float_as_uint(x), __float_as_uint(x));
  return fmaxf(__uint_as_float(r.x), __uint_as_float(r.y));
}
__device__ __forceinline__ unsigned cvtpk(float a, float b) {
  unsigned r;
  asm("v_cvt_pk_bf16_f32 %0, %1, %2" : "=v"(r) : "v"(a), "v"(b));
  return r;
}
__device__ __forceinline__ float F3(float a, float b, float c) {
  return fmaxf(fmaxf(a, b), c);  // fuses to v_max3_f32
}

// ---------- f32 -> bf16 casts ----------
__global__ __launch_bounds__(256) void cast_bf16_kernel(
    const float* __restrict__ in, unsigned short* __restrict__ out, int n4) {
  int i = blockIdx.x * 256 + threadIdx.x;
  int stride = gridDim.x * 256;
  for (; i < n4; i += stride) {
    float4 f = reinterpret_cast<const float4*>(in)[i];
    ushort4 s;
    s.x = f2bf(f.x); s.y = f2bf(f.y); s.z = f2bf(f.z); s.w = f2bf(f.w);
    reinterpret_cast<ushort4*>(out)[i] = s;
  }
}

// all four 2048x2048 weights in one launch (1,048,576 float4 each)
__global__ __launch_bounds__(256) void cast_w4_kernel(
    const float* __restrict__ w0, const float* __restrict__ w1,
    const float* __restrict__ w2, const float* __restrict__ w3,
    unsigned short* __restrict__ o0, unsigned short* __restrict__ o1,
    unsigned short* __restrict__ o2, unsigned short* __restrict__ o3) {
  int i = blockIdx.x * 256 + threadIdx.x;
  int stride = gridDim.x * 256;
  for (; i < 4194304; i += stride) {
    int sel = i >> 20;
    const float* src = sel == 0 ? w0 : sel == 1 ? w1 : sel == 2 ? w2 : w3;
    unsigned short* dst = sel == 0 ? o0 : sel == 1 ? o1 : sel == 2 ? o2 : o3;
    int j = i & 1048575;
    float4 f = reinterpret_cast<const float4*>(src)[j];
    ushort4 s;
    s.x = f2bf(f.x); s.y = f2bf(f.y); s.z = f2bf(f.z); s.w = f2bf(f.w);
    reinterpret_cast<ushort4*>(dst)[j] = s;
  }
}

// ---------- fused QKV GEMM: C_sel[m, c] = sum_k A[m,k]*W_sel[c,k] + b_sel[c] ----------
// logical N = 6144 (three 2048 outputs selected by column block). 128x128 tile.
__global__ __launch_bounds__(256) void gemm_qkv(
    const unsigned short* __restrict__ A,
    const unsigned short* __restrict__ W0, const unsigned short* __restrict__ W1,
    const unsigned short* __restrict__ W2,
    const float* __restrict__ b0, const float* __restrict__ b1,
    const float* __restrict__ b2,
    unsigned short* __restrict__ C0, unsigned short* __restrict__ C1,
    unsigned short* __restrict__ C2) {
  const int K = 2048, N = 2048;
  // XCD-bijective swizzle (1536 % 8 == 0)
  const int lin = blockIdx.x + blockIdx.y * gridDim.x;
  const int cpx = (gridDim.x * gridDim.y) >> 3;
  const int swz = (lin & 7) * cpx + (lin >> 3);
  const int bx = swz % gridDim.x, by = swz / gridDim.x;

  const int gcol = bx * 128;
  const int sel = gcol >> 11;
  const unsigned short* B = sel == 0 ? W0 : sel == 1 ? W1 : W2;
  const float* bias = sel == 0 ? b0 : sel == 1 ? b1 : b2;
  unsigned short* Cp = sel == 0 ? C0 : sel == 1 ? C1 : C2;
  const int col0 = gcol & 2047;
  const int row0 = by * 128;

  __shared__ unsigned short As[128 * 64];
  __shared__ unsigned short Bs[128 * 64];
  const int tid = threadIdx.x;
  const int lane = tid & 63;
  const int wid = tid >> 6;
  const int wr = wid >> 1, wc = wid & 1;
  const int l15 = lane & 15, l4 = lane >> 4;

  f32x4 acc[4][4] = {};

  const int srow = lane >> 3;
  const int scol = (lane & 7) * 8;

  for (int kt = 0; kt < K; kt += 64) {
    __syncthreads();
#pragma unroll
    for (int i = 0; i < 4; ++i) {
      int c = wid * 4 + i;
      GLD16(A + (size_t)(row0 + c * 8 + srow) * K + kt + scol, &As[c * 512]);
      GLD16(B + (size_t)(col0 + c * 8 + srow) * K + kt + scol, &Bs[c * 512]);
    }
    __syncthreads();
#pragma unroll
    for (int ks = 0; ks < 2; ++ks) {
      const int ko = ks * 32 + l4 * 8;
      bf16x8 af[4], bfr[4];
#pragma unroll
      for (int mi = 0; mi < 4; ++mi)
        af[mi] = *(const bf16x8*)&As[(wr * 64 + mi * 16 + l15) * 64 + ko];
#pragma unroll
      for (int ni = 0; ni < 4; ++ni)
        bfr[ni] = *(const bf16x8*)&Bs[(wc * 64 + ni * 16 + l15) * 64 + ko];
#pragma unroll
      for (int mi = 0; mi < 4; ++mi)
#pragma unroll
        for (int ni = 0; ni < 4; ++ni)
          acc[mi][ni] = __builtin_amdgcn_mfma_f32_16x16x32_bf16(
              af[mi], bfr[ni], acc[mi][ni], 0, 0, 0);
    }
  }

#pragma unroll
  for (int mi = 0; mi < 4; ++mi)
#pragma unroll
    for (int ni = 0; ni < 4; ++ni)
#pragma unroll
      for (int r = 0; r < 4; ++r) {
        int row = row0 + wr * 64 + mi * 16 + l4 * 4 + r;
        int col = col0 + wc * 64 + ni * 16 + l15;
        float v = acc[mi][ni][r] + bias[col];
        Cp[(size_t)row * N + col] = f2bf(v);
      }
}

// ---------- bf16 NT GEMM (f32 out, for the Wo projection) ----------
__global__ __launch_bounds__(256) void gemm_bt_f32(
    const unsigned short* __restrict__ A, const unsigned short* __restrict__ B,
    const float* __restrict__ bias, float* __restrict__ Cp, int M, int N, int K) {
  const int lin = blockIdx.x + blockIdx.y * gridDim.x;
  const int cpx = (gridDim.x * gridDim.y) >> 3;
  const int swz = (lin & 7) * cpx + (lin >> 3);
  const int bx = swz % gridDim.x, by = swz / gridDim.x;

  __shared__ unsigned short As[128 * 64];
  __shared__ unsigned short Bs[128 * 64];
  const int tid = threadIdx.x;
  const int lane = tid & 63;
  const int wid = tid >> 6;
  const int wr = wid >> 1, wc = wid & 1;
  const int l15 = lane & 15, l4 = lane >> 4;
  const int row0 = by * 128, col0 = bx * 128;

  f32x4 acc[4][4] = {};

  const int srow = lane >> 3;
  const int scol = (lane & 7) * 8;

  for (int kt = 0; kt < K; kt += 64) {
    __syncthreads();
#pragma unroll
    for (int i = 0; i < 4; ++i) {
      int c = wid * 4 + i;
      GLD16(A + (size_t)(row0 + c * 8 + srow) * K + kt + scol, &As[c * 512]);
      GLD16(B + (size_t)(col0 + c * 8 + srow) * K + kt + scol, &Bs[c * 512]);
    }
    __syncthreads();
#pragma unroll
    for (int ks = 0; ks < 2; ++ks) {
      const int ko = ks * 32 + l4 * 8;
      bf16x8 af[4], bfr[4];
#pragma unroll
      for (int mi = 0; mi < 4; ++mi)
        af[mi] = *(const bf16x8*)&As[(wr * 64 + mi * 16 + l15) * 64 + ko];
#pragma unroll
      for (int ni = 0; ni < 4; ++ni)
        bfr[ni] = *(const bf16x8*)&Bs[(wc * 64 + ni * 16 + l15) * 64 + ko];
#pragma unroll
      for (int mi = 0; mi < 4; ++mi)
#pragma unroll
        for (int ni = 0; ni < 4; ++ni)
          acc[mi][ni] = __builtin_amdgcn_mfma_f32_16x16x32_bf16(
              af[mi], bfr[ni], acc[mi][ni], 0, 0, 0);
    }
  }

#pragma unroll
  for (int mi = 0; mi < 4; ++mi)
#pragma unroll
    for (int ni = 0; ni < 4; ++ni)
#pragma unroll
      for (int r = 0; r < 4; ++r) {
        int row = row0 + wr * 64 + mi * 16 + l4 * 4 + r;
        int col = col0 + wc * 64 + ni * 16 + l15;
        Cp[(size_t)row * N + col] = acc[mi][ni][r] + bias[col];
      }
}

// ---------- combined in-place RMS norm: Q rows then K rows ----------
__global__ __launch_bounds__(256) void rmsnorm2_kernel(
    unsigned short* __restrict__ Qb, unsigned short* __restrict__ Kb,
    const float* __restrict__ qw, const float* __restrict__ kw) {
  const int row = blockIdx.x;
  unsigned short* p;
  const float* w;
  if (row < 4096) { p = Qb + (size_t)row * 2048; w = qw; }
  else            { p = Kb + (size_t)(row - 4096) * 2048; w = kw; }
  const int tid = threadIdx.x;
  u16x8 v = *(const u16x8*)&p[tid * 8];
  float f[8];
  float ss = 0.f;
#pragma unroll
  for (int j = 0; j < 8; ++j) { f[j] = bf2f(v[j]); ss += f[j] * f[j]; }
#pragma unroll
  for (int m = 1; m < 64; m <<= 1) ss += __shfl_xor(ss, m, 64);
  __shared__ float red[4];
  const int wid = tid >> 6, lane = tid & 63;
  if (lane == 0) red[wid] = ss;
  __syncthreads();
  float tot = red[0] + red[1] + red[2] + red[3];
  float rs = rsqrtf(tot * (1.0f / 2048.0f) + 1e-6f);
  u16x8 o;
#pragma unroll
  for (int j = 0; j < 8; ++j) o[j] = f2bf(f[j] * rs * w[tid * 8 + j]);
  *(u16x8*)&p[tid * 8] = o;
}

// ---------- flash attention, swapped-operand 32x32, double-buffered ----------
// 1024 blocks (XCD-swizzled), 4 waves/block, 32 q/wave, KVBLK=64.
// l-sum via ones-MFMA; hoisted swizzled fragment offsets.
__global__ __launch_bounds__(256, 4) void flash_attn(
    const unsigned short* __restrict__ Q, const unsigned short* __restrict__ K,
    const unsigned short* __restrict__ V, unsigned short* __restrict__ O) {
  __shared__ unsigned short Ks[2][64 * 64];   // [key][dh], swizzled
  __shared__ unsigned short Vs[2][64 * 64];   // transposed [dh][key], swizzled
  const int bid = blockIdx.x;
  const int sw = (bid & 7) * 128 + (bid >> 3);   // XCD-chunked (1024 % 8 == 0)
  const int h = sw >> 5;
  const int q0 = (sw & 31) * 128;
  const int tid = threadIdx.x, lane = tid & 63, wid = tid >> 6;
  const int l31 = lane & 31, hi = lane >> 5;

  // staging geometry (per lane)
  const int kr0 = wid * 16 + (lane >> 3);    // K rows kr0, kr0+8
  const int kc0 = (lane & 7) * 8;
  const int vkey = (tid & 31) * 2;           // V key pair
  const int vd0 = (tid >> 5) * 8;            // V dh group

  // Q B-frags, pre-scaled by 0.125*log2(e) (exp2-domain softmax)
  const float QSCALE = 0.125f * 1.44269504f;
  bf16x8 qf[4];
  {
    const int qrow = q0 + wid * 32 + l31;
#pragma unroll
    for (int kt = 0; kt < 4; ++kt) {
      bf16x8 raw = *(const bf16x8*)&Q[(size_t)qrow * 2048 + h * 64 + kt * 16 + hi * 8];
#pragma unroll
      for (int j = 0; j < 8; ++j) qf[kt][j] = (__bf16)((float)raw[j] * QSCALE);
    }
  }

  // hoisted swizzled fragment element-offsets (identical for Ks and Vs reads)
  int off[2][4];
#pragma unroll
  for (int kb = 0; kb < 2; ++kb) {
    const int row = kb * 32 + l31;
    const int sel = (((row & 7) ^ ((row >> 3) & 7)) & 7) << 3;
#pragma unroll
    for (int kt = 0; kt < 4; ++kt)
      off[kb][kt] = row * 64 + ((kt * 16 + hi * 8) ^ sel);
  }

  bf16x8 onesf;
#pragma unroll
  for (int j = 0; j < 8; ++j) onesf[j] = (__bf16)1.0f;

  float m_r = -1e30f;
  f32x16 oa[2] = {};
  f32x16 lacc = {};   // lacc[0] = running sum of P (ones-MFMA)

  u16x8 kreg0, kreg1, vreg0, vreg1;
  auto loadKV = [&](int kt0) {
    kreg0 = *(const u16x8*)&K[(size_t)(kt0 + kr0) * 2048 + h * 64 + kc0];
    kreg1 = *(const u16x8*)&K[(size_t)(kt0 + kr0 + 8) * 2048 + h * 64 + kc0];
    vreg0 = *(const u16x8*)&V[(size_t)(kt0 + vkey) * 2048 + h * 64 + vd0];
    vreg1 = *(const u16x8*)&V[(size_t)(kt0 + vkey + 1) * 2048 + h * 64 + vd0];
  };
  auto writeKV = [&](int b) {
    *(u16x8*)&Ks[b][kr0 * 64 + swzc(kr0, kc0)] = kreg0;
    *(u16x8*)&Ks[b][(kr0 + 8) * 64 + swzc(kr0 + 8, kc0)] = kreg1;
#pragma unroll
    for (int d = 0; d < 8; ++d) {
      int row = vd0 + d;
      *(unsigned*)&Vs[b][row * 64 + swzc(row, vkey)] =
          (unsigned)vreg0[d] | ((unsigned)vreg1[d] << 16);
    }
  };

  // prologue: stage tile 0 into buffer 0
  loadKV(0);
  writeKV(0);
  __syncthreads();

  for (int t = 0; t < 64; ++t) {
    const int cur = t & 1;
    if (t < 63) loadKV((t + 1) * 64);

    const unsigned short* Kc = Ks[cur];
    const unsigned short* Vc = Vs[cur];

    // ---- S^T = mfma(K, Q): lane holds 32 scores of query q = l31 ----
    f32x16 st[2];
    __builtin_amdgcn_s_setprio(1);
#pragma unroll
    for (int kb = 0; kb < 2; ++kb) {
      f32x16 a = {};
#pragma unroll
      for (int kt = 0; kt < 4; ++kt) {
        bf16x8 kf = *(const bf16x8*)&Kc[off[kb][kt]];
        a = __builtin_amdgcn_mfma_f32_32x32x16_bf16(kf, qf[kt], a, 0, 0, 0);
      }
      st[kb] = a;
    }
    __builtin_amdgcn_s_setprio(0);

    // ---- max reduce (max3 triples) ----
    float t8[8];
#pragma unroll
    for (int j = 0; j < 8; ++j)
      t8[j] = fmaxf(F3(st[0][2 * j], st[0][2 * j + 1], st[1][2 * j]),
                    st[1][2 * j + 1]);
    float tmax = pair_max(F3(F3(t8[0], t8[1], t8[2]), F3(t8[3], t8[4], t8[5]),
                             fmaxf(t8[6], t8[7])));

    // ---- defer-max rescale (T13, THR=11 in log2 domain) ----
    if (!__all(tmax <= m_r + 11.0f)) {
      float mn = fmaxf(m_r, tmax);
      float corr = __builtin_amdgcn_exp2f(m_r - mn);
      lacc[0] *= corr;
#pragma unroll
      for (int dv = 0; dv < 2; ++dv)
#pragma unroll
        for (int r = 0; r < 16; ++r) oa[dv][r] *= corr;
      m_r = mn;
    }

    // ---- P = exp2(S - m), pack to bf16 pairs ----
    unsigned pk[16];
#pragma unroll
    for (int kb = 0; kb < 2; ++kb)
#pragma unroll
      for (int j = 0; j < 8; ++j) {
        float pa = __builtin_amdgcn_exp2f(st[kb][2 * j] - m_r);
        float pb = __builtin_amdgcn_exp2f(st[kb][2 * j + 1] - m_r);
        pk[kb * 8 + j] = cvtpk(pa, pb);
      }

    // ---- build PV B-frags in-register via permlane32_swap ----
    bf16x8 pfrag[4];
#pragma unroll
    for (int kt = 0; kt < 4; ++kt) {
      u32x2 sa = plswap(pk[4 * kt + 0], pk[4 * kt + 2]);
      u32x2 sb = plswap(pk[4 * kt + 1], pk[4 * kt + 3]);
      union { u32x4 u; bf16x8 b; } w;
      w.u.x = sa.x; w.u.y = sb.x; w.u.z = sa.y; w.u.w = sb.y;
      pfrag[kt] = w.b;
    }

    // ---- l-sum via ones-MFMA + PV: O^T[dv] += V^T-frag @ P^T-frag ----
    __builtin_amdgcn_s_setprio(1);
#pragma unroll
    for (int kt = 0; kt < 4; ++kt)
      lacc = __builtin_amdgcn_mfma_f32_32x32x16_bf16(onesf, pfrag[kt], lacc, 0, 0, 0);
#pragma unroll
    for (int dv = 0; dv < 2; ++dv) {
#pragma unroll
      for (int kt = 0; kt < 4; ++kt) {
        bf16x8 vf = *(const bf16x8*)&Vc[off[dv][kt]];
        oa[dv] = __builtin_amdgcn_mfma_f32_32x32x16_bf16(vf, pfrag[kt], oa[dv], 0, 0, 0);
      }
    }
    __builtin_amdgcn_s_setprio(0);

    // ---- write next buffer, single barrier ----
    if (t < 63) {
      writeKV(cur ^ 1);
      __syncthreads();
    }
  }

  // ---- epilogue: vectorized O store ----
  const float inv = 1.0f / lacc[0];
  const int qrow = q0 + wid * 32 + l31;
#pragma unroll
  for (int dv = 0; dv < 2; ++dv)
#pragma unroll
    for (int tq = 0; tq < 4; ++tq) {
      unsigned w0 = cvtpk(oa[dv][4 * tq + 0] * inv, oa[dv][4 * tq + 1] * inv);
      unsigned w1 = cvtpk(oa[dv][4 * tq + 2] * inv, oa[dv][4 * tq + 3] * inv);
      int dh = 32 * dv + 8 * tq + 4 * hi;
      u32x2 w2 = {w0, w1};
      *(u32x2*)&O[(size_t)qrow * 2048 + h * 64 + dh] = w2;
    }
}

// ---------- launch ----------
extern "C" void kernel_launch(void* const* d_in, const int* in_sizes, int n_in,
                              void* d_out, int out_size, void* d_ws, size_t ws_size,
                              hipStream_t stream) {
  const float* x  = (const float*)d_in[0];
  const float* Wq = (const float*)d_in[1];
  const float* bq = (const float*)d_in[2];
  const float* Wk = (const float*)d_in[3];
  const float* bk = (const float*)d_in[4];
  const float* Wv = (const float*)d_in[5];
  const float* bv = (const float*)d_in[6];
  const float* qn = (const float*)d_in[7];
  const float* kn = (const float*)d_in[8];
  const float* Wo = (const float*)d_in[9];
  const float* bo = (const float*)d_in[10];

  char* w = (char*)d_ws;
  unsigned short* Xbf = (unsigned short*)(w);                 // reused for O
  unsigned short* Wqb = (unsigned short*)(w + 16777216);
  unsigned short* Wkb = (unsigned short*)(w + 25165824);
  unsigned short* Wvb = (unsigned short*)(w + 33554432);
  unsigned short* Wob = (unsigned short*)(w + 41943040);
  unsigned short* Qb  = (unsigned short*)(w + 50331648);
  unsigned short* Kb  = (unsigned short*)(w + 67108864);
  unsigned short* Vb  = (unsigned short*)(w + 83886080);
  unsigned short* Ob  = Xbf;

  cast_bf16_kernel<<<1024, 256, 0, stream>>>(x, Xbf, 8388608 / 4);
  cast_w4_kernel<<<2048, 256, 0, stream>>>(Wq, Wk, Wv, Wo, Wqb, Wkb, Wvb, Wob);

  gemm_qkv<<<dim3(48, 32), 256, 0, stream>>>(Xbf, Wqb, Wkb, Wvb, bq, bk, bv,
                                             Qb, Kb, Vb);

  rmsnorm2_kernel<<<8192, 256, 0, stream>>>(Qb, Kb, qn, kn);

  flash_attn<<<1024, 256, 0, stream>>>(Qb, Kb, Vb, Ob);

  gemm_bt_f32<<<dim3(16, 32), 256, 0, stream>>>(Ob, Wob, bo, (float*)d_out,
                                                4096, 2048, 2048);
}

// Round 6
// 395.356 us; speedup vs baseline: 1.1199x; 1.1199x over previous
//
#include <hip/hip_runtime.h>

// ---------- types ----------
typedef __bf16 bf16x8 __attribute__((ext_vector_type(8)));
typedef float f32x4 __attribute__((ext_vector_type(4)));
typedef float f32x16 __attribute__((ext_vector_type(16)));
typedef unsigned short u16x8 __attribute__((ext_vector_type(8)));
typedef unsigned u32x2 __attribute__((ext_vector_type(2)));
typedef unsigned u32x4 __attribute__((ext_vector_type(4)));

__device__ __forceinline__ unsigned short f2bf(float f) {
  union { float f; unsigned u; } v; v.f = f;
  unsigned r = (v.u + 0x7fffu + ((v.u >> 16) & 1u)) >> 16;
  return (unsigned short)r;
}
__device__ __forceinline__ float bf2f(unsigned short s) {
  union { unsigned u; float f; } v; v.u = ((unsigned)s) << 16;
  return v.f;
}

#define GLD16(g, l)                                                        \
  __builtin_amdgcn_global_load_lds(                                        \
      (const __attribute__((address_space(1))) void*)(g),                  \
      (__attribute__((address_space(3))) void*)(l), 16, 0, 0)

// XOR swizzle for 64-element (128B) rows (flash_attn tiles).
__device__ __forceinline__ int swzc(int row, int colel) {
  return colel ^ ((((row & 7) ^ ((row >> 3) & 7)) & 7) << 3);
}

__device__ __forceinline__ u32x2 plswap(unsigned a, unsigned b) {
  return __builtin_amdgcn_permlane32_swap(a, b, false, false);
}
__device__ __forceinline__ float pair_max(float x) {
  u32x2 r = plswap(__float_as_uint(x), __float_as_uint(x));
  return fmaxf(__uint_as_float(r.x), __uint_as_float(r.y));
}
__device__ __forceinline__ float pair_sum(float x) {
  u32x2 r = plswap(__float_as_uint(x), __float_as_uint(x));
  return __uint_as_float(r.x) + __uint_as_float(r.y);
}
__device__ __forceinline__ unsigned cvtpk(float a, float b) {
  unsigned r;
  asm("v_cvt_pk_bf16_f32 %0, %1, %2" : "=v"(r) : "v"(a), "v"(b));
  return r;
}
__device__ __forceinline__ float F3(float a, float b, float c) {
  return fmaxf(fmaxf(a, b), c);  // fuses to v_max3_f32
}

// ---------- f32 -> bf16 casts ----------
__global__ __launch_bounds__(256) void cast_bf16_kernel(
    const float* __restrict__ in, unsigned short* __restrict__ out, int n4) {
  int i = blockIdx.x * 256 + threadIdx.x;
  int stride = gridDim.x * 256;
  for (; i < n4; i += stride) {
    float4 f = reinterpret_cast<const float4*>(in)[i];
    ushort4 s;
    s.x = f2bf(f.x); s.y = f2bf(f.y); s.z = f2bf(f.z); s.w = f2bf(f.w);
    reinterpret_cast<ushort4*>(out)[i] = s;
  }
}

__global__ __launch_bounds__(256) void cast_w4_kernel(
    const float* __restrict__ w0, const float* __restrict__ w1,
    const float* __restrict__ w2, const float* __restrict__ w3,
    unsigned short* __restrict__ o0, unsigned short* __restrict__ o1,
    unsigned short* __restrict__ o2, unsigned short* __restrict__ o3) {
  int i = blockIdx.x * 256 + threadIdx.x;
  int stride = gridDim.x * 256;
  for (; i < 4194304; i += stride) {
    int sel = i >> 20;
    const float* src = sel == 0 ? w0 : sel == 1 ? w1 : sel == 2 ? w2 : w3;
    unsigned short* dst = sel == 0 ? o0 : sel == 1 ? o1 : sel == 2 ? o2 : o3;
    int j = i & 1048575;
    float4 f = reinterpret_cast<const float4*>(src)[j];
    ushort4 s;
    s.x = f2bf(f.x); s.y = f2bf(f.y); s.z = f2bf(f.z); s.w = f2bf(f.w);
    reinterpret_cast<ushort4*>(dst)[j] = s;
  }
}

// ---------- 8-phase counted-vmcnt NT GEMM ----------
// C_sel[m,c] = sum_k A[m,k]*W_sel[c,k] + b_sel[c].  BM=BN=128, BK=64,
// 256 threads (4 waves, 2Mx2N), 2 blocks/CU (64KB LDS).
// LDS: col-half planes [buf][ks][128][32] (A at 0, B at +16384 elements),
// each plane staged linearly via global_load_lds with pre-swizzled source.
// 8 phases/iter over 2 K-steps; stages one (A or B, ks) unit per phase;
// vmcnt(8) at even-phase ends only (counted, never 0 in steady state).

#define STG_A(STEP, KS, BUF)                                                   \
  GLD16(Ag + (size_t)(row0 + st_row0) * 2048 + (STEP) * 64 + (KS) * 32 +       \
            st_col0,                                                           \
        &ls[((BUF) * 2 + (KS)) * 4096 + (wid * 2) * 512]);                     \
  GLD16(Ag + (size_t)(row0 + st_row1) * 2048 + (STEP) * 64 + (KS) * 32 +       \
            st_col1,                                                           \
        &ls[((BUF) * 2 + (KS)) * 4096 + (wid * 2 + 1) * 512]);

#define STG_B(STEP, KS, BUF)                                                   \
  GLD16(Bg + (size_t)(col0 + st_row0) * 2048 + (STEP) * 64 + (KS) * 32 +       \
            st_col0,                                                           \
        &ls[16384 + ((BUF) * 2 + (KS)) * 4096 + (wid * 2) * 512]);             \
  GLD16(Bg + (size_t)(col0 + st_row1) * 2048 + (STEP) * 64 + (KS) * 32 +       \
            st_col1,                                                           \
        &ls[16384 + ((BUF) * 2 + (KS)) * 4096 + (wid * 2 + 1) * 512]);

#define VM8 asm volatile("s_waitcnt vmcnt(8)" ::: "memory");
#define VM4 asm volatile("s_waitcnt vmcnt(4)" ::: "memory");
#define VM0 asm volatile("s_waitcnt vmcnt(0)" ::: "memory");

#define PHASE(BUF, KS, MQ, RB, STG, VMW)                                       \
  {                                                                            \
    af0 = *(const bf16x8*)&ls[((BUF) * 2 + (KS)) * 4096 + offA[(MQ) * 2 + 0]]; \
    af1 = *(const bf16x8*)&ls[((BUF) * 2 + (KS)) * 4096 + offA[(MQ) * 2 + 1]]; \
    if (RB) {                                                                  \
      bfr[0] = *(const bf16x8*)&ls[16384 + ((BUF) * 2 + (KS)) * 4096 + offB[0]]; \
      bfr[1] = *(const bf16x8*)&ls[16384 + ((BUF) * 2 + (KS)) * 4096 + offB[1]]; \
      bfr[2] = *(const bf16x8*)&ls[16384 + ((BUF) * 2 + (KS)) * 4096 + offB[2]]; \
      bfr[3] = *(const bf16x8*)&ls[16384 + ((BUF) * 2 + (KS)) * 4096 + offB[3]]; \
    }                                                                          \
    STG;                                                                       \
    __builtin_amdgcn_s_barrier();                                              \
    __builtin_amdgcn_s_setprio(1);                                             \
    acc[(MQ) * 2 + 0][0] = __builtin_amdgcn_mfma_f32_16x16x32_bf16(            \
        af0, bfr[0], acc[(MQ) * 2 + 0][0], 0, 0, 0);                           \
    acc[(MQ) * 2 + 0][1] = __builtin_amdgcn_mfma_f32_16x16x32_bf16(            \
        af0, bfr[1], acc[(MQ) * 2 + 0][1], 0, 0, 0);                           \
    acc[(MQ) * 2 + 0][2] = __builtin_amdgcn_mfma_f32_16x16x32_bf16(            \
        af0, bfr[2], acc[(MQ) * 2 + 0][2], 0, 0, 0);                           \
    acc[(MQ) * 2 + 0][3] = __builtin_amdgcn_mfma_f32_16x16x32_bf16(            \
        af0, bfr[3], acc[(MQ) * 2 + 0][3], 0, 0, 0);                           \
    acc[(MQ) * 2 + 1][0] = __builtin_amdgcn_mfma_f32_16x16x32_bf16(            \
        af1, bfr[0], acc[(MQ) * 2 + 1][0], 0, 0, 0);                           \
    acc[(MQ) * 2 + 1][1] = __builtin_amdgcn_mfma_f32_16x16x32_bf16(            \
        af1, bfr[1], acc[(MQ) * 2 + 1][1], 0, 0, 0);                           \
    acc[(MQ) * 2 + 1][2] = __builtin_amdgcn_mfma_f32_16x16x32_bf16(            \
        af1, bfr[2], acc[(MQ) * 2 + 1][2], 0, 0, 0);                           \
    acc[(MQ) * 2 + 1][3] = __builtin_amdgcn_mfma_f32_16x16x32_bf16(            \
        af1, bfr[3], acc[(MQ) * 2 + 1][3], 0, 0, 0);                           \
    __builtin_amdgcn_s_setprio(0);                                             \
    VMW;                                                                       \
    __builtin_amdgcn_s_barrier();                                              \
  }

template <int F32OUT>
__global__ __launch_bounds__(256, 2) void gemm8p(
    const unsigned short* __restrict__ Ag,
    const unsigned short* __restrict__ W0, const unsigned short* __restrict__ W1,
    const unsigned short* __restrict__ W2,
    const float* __restrict__ b0, const float* __restrict__ b1,
    const float* __restrict__ b2,
    void* __restrict__ C0, void* __restrict__ C1, void* __restrict__ C2) {
  extern __shared__ __align__(16) unsigned short ls[];  // 32768 els = 64KB

  // XCD-bijective swizzle (grid total divisible by 8)
  const int lin = blockIdx.y * gridDim.x + blockIdx.x;
  const int cpx = (gridDim.x * gridDim.y) >> 3;
  const int swz = (lin & 7) * cpx + (lin >> 3);
  const int bx = swz % gridDim.x, by = swz / gridDim.x;

  const int gcol = bx * 128;
  const int sel = gcol >> 11;
  const unsigned short* Bg = sel == 0 ? W0 : sel == 1 ? W1 : W2;
  const float* bias = sel == 0 ? b0 : sel == 1 ? b1 : b2;
  void* Cp = sel == 0 ? C0 : sel == 1 ? C1 : C2;
  const int col0 = gcol & 2047;
  const int row0 = by * 128;

  const int tid = threadIdx.x, lane = tid & 63, wid = tid >> 6;
  const int l15 = lane & 15, l4 = lane >> 4;
  const int wm = wid >> 1, wn = wid & 1;

  // staging geometry: chunk ci = wid*2 + i (16 rows each, 8 chunks/plane)
  const int ci0 = wid * 2, ci1 = wid * 2 + 1;
  const int st_row0 = ci0 * 16 + (lane >> 2);
  const int st_row1 = ci1 * 16 + (lane >> 2);
  const int sl2a = ((lane >> 2) & 3) ^ ((lane >> 4) & 3);
  const int st_col0 = (((lane & 3) ^ (sl2a ^ (ci0 & 3))) * 8);
  const int st_col1 = (((lane & 3) ^ (sl2a ^ (ci1 & 3))) * 8);

  // fragment read offsets (elements within a plane), swizzle-consistent
  const int lsel = (l15 & 3) ^ ((l15 >> 2) & 3);
  int offA[4], offB[4];
#pragma unroll
  for (int f = 0; f < 4; ++f)
    offA[f] = (wm * 64 + f * 16 + l15) * 32 + ((l4 ^ lsel ^ (f & 3)) & 3) * 8;
#pragma unroll
  for (int ni = 0; ni < 4; ++ni)
    offB[ni] =
        (wn * 64 + ni * 16 + l15) * 32 + ((l4 ^ lsel ^ ((wn * 4 + ni) & 3)) & 3) * 8;

  f32x4 acc[4][4] = {};
  bf16x8 af0, af1, bfr[4];

  // prologue: stage E0(ks0,ks1), O0(ks0); wait oldest unit, barrier
  STG_A(0, 0, 0); STG_B(0, 0, 0);
  STG_A(0, 1, 0); STG_B(0, 1, 0);
  STG_A(1, 0, 1); STG_B(1, 0, 1);
  VM8;
  __builtin_amdgcn_s_barrier();

  for (int it = 0; it < 15; ++it) {
    const int sE = 2 * it, sO = sE + 1;
    PHASE(0, 0, 0, 1, STG_A(sO, 1, 1), );
    PHASE(0, 0, 1, 0, STG_B(sO, 1, 1), VM8);
    PHASE(0, 1, 0, 1, STG_A(sE + 2, 0, 0), );
    PHASE(0, 1, 1, 0, STG_B(sE + 2, 0, 0), VM8);
    PHASE(1, 0, 0, 1, STG_A(sE + 2, 1, 0), );
    PHASE(1, 0, 1, 0, STG_B(sE + 2, 1, 0), VM8);
    PHASE(1, 1, 0, 1, STG_A(sO + 2, 0, 1), );
    PHASE(1, 1, 1, 0, STG_B(sO + 2, 0, 1), VM8);
  }
  // epilogue iteration (steps 30,31): stage only O15 ks1; drain 8->4->0
  PHASE(0, 0, 0, 1, STG_A(31, 1, 1), );
  PHASE(0, 0, 1, 0, STG_B(31, 1, 1), VM8);
  PHASE(0, 1, 0, 1, , );
  PHASE(0, 1, 1, 0, , VM4);
  PHASE(1, 0, 0, 1, , );
  PHASE(1, 0, 1, 0, , VM0);
  PHASE(1, 1, 0, 1, , );
  PHASE(1, 1, 1, 0, , );

  // C-write
#pragma unroll
  for (int f = 0; f < 4; ++f)
#pragma unroll
    for (int ni = 0; ni < 4; ++ni)
#pragma unroll
      for (int r = 0; r < 4; ++r) {
        int row = row0 + wm * 64 + f * 16 + l4 * 4 + r;
        int col = col0 + wn * 64 + ni * 16 + l15;
        float v = acc[f][ni][r] + bias[col];
        if (F32OUT)
          ((float*)Cp)[(size_t)row * 2048 + col] = v;
        else
          ((unsigned short*)Cp)[(size_t)row * 2048 + col] = f2bf(v);
      }
}

// ---------- combined in-place RMS norm: Q rows then K rows ----------
__global__ __launch_bounds__(256) void rmsnorm2_kernel(
    unsigned short* __restrict__ Qb, unsigned short* __restrict__ Kb,
    const float* __restrict__ qw, const float* __restrict__ kw) {
  const int row = blockIdx.x;
  unsigned short* p;
  const float* w;
  if (row < 4096) { p = Qb + (size_t)row * 2048; w = qw; }
  else            { p = Kb + (size_t)(row - 4096) * 2048; w = kw; }
  const int tid = threadIdx.x;
  u16x8 v = *(const u16x8*)&p[tid * 8];
  float f[8];
  float ss = 0.f;
#pragma unroll
  for (int j = 0; j < 8; ++j) { f[j] = bf2f(v[j]); ss += f[j] * f[j]; }
#pragma unroll
  for (int m = 1; m < 64; m <<= 1) ss += __shfl_xor(ss, m, 64);
  __shared__ float red[4];
  const int wid = tid >> 6, lane = tid & 63;
  if (lane == 0) red[wid] = ss;
  __syncthreads();
  float tot = red[0] + red[1] + red[2] + red[3];
  float rs = rsqrtf(tot * (1.0f / 2048.0f) + 1e-6f);
  u16x8 o;
#pragma unroll
  for (int j = 0; j < 8; ++j) o[j] = f2bf(f[j] * rs * w[tid * 8 + j]);
  *(u16x8*)&p[tid * 8] = o;
}

// ---------- flash attention, swapped-operand 32x32, double-buffered ----------
// (round-4 structure: VALU l-sum; hoisted swizzled fragment offsets)
__global__ __launch_bounds__(256, 4) void flash_attn(
    const unsigned short* __restrict__ Q, const unsigned short* __restrict__ K,
    const unsigned short* __restrict__ V, unsigned short* __restrict__ O) {
  __shared__ unsigned short Ks[2][64 * 64];   // [key][dh], swizzled
  __shared__ unsigned short Vs[2][64 * 64];   // transposed [dh][key], swizzled
  const int bid = blockIdx.x;
  const int sw = (bid & 7) * 128 + (bid >> 3);   // XCD-chunked (1024 % 8 == 0)
  const int h = sw >> 5;
  const int q0 = (sw & 31) * 128;
  const int tid = threadIdx.x, lane = tid & 63, wid = tid >> 6;
  const int l31 = lane & 31, hi = lane >> 5;

  const int kr0 = wid * 16 + (lane >> 3);
  const int kc0 = (lane & 7) * 8;
  const int vkey = (tid & 31) * 2;
  const int vd0 = (tid >> 5) * 8;

  const float QSCALE = 0.125f * 1.44269504f;
  bf16x8 qf[4];
  {
    const int qrow = q0 + wid * 32 + l31;
#pragma unroll
    for (int kt = 0; kt < 4; ++kt) {
      bf16x8 raw = *(const bf16x8*)&Q[(size_t)qrow * 2048 + h * 64 + kt * 16 + hi * 8];
#pragma unroll
      for (int j = 0; j < 8; ++j) qf[kt][j] = (__bf16)((float)raw[j] * QSCALE);
    }
  }

  int off[2][4];
#pragma unroll
  for (int kb = 0; kb < 2; ++kb) {
    const int row = kb * 32 + l31;
    const int sl = (((row & 7) ^ ((row >> 3) & 7)) & 7) << 3;
#pragma unroll
    for (int kt = 0; kt < 4; ++kt)
      off[kb][kt] = row * 64 + ((kt * 16 + hi * 8) ^ sl);
  }

  float m_r = -1e30f, l_r = 0.f;
  f32x16 oa[2] = {};

  u16x8 kreg0, kreg1, vreg0, vreg1;
  auto loadKV = [&](int kt0) {
    kreg0 = *(const u16x8*)&K[(size_t)(kt0 + kr0) * 2048 + h * 64 + kc0];
    kreg1 = *(const u16x8*)&K[(size_t)(kt0 + kr0 + 8) * 2048 + h * 64 + kc0];
    vreg0 = *(const u16x8*)&V[(size_t)(kt0 + vkey) * 2048 + h * 64 + vd0];
    vreg1 = *(const u16x8*)&V[(size_t)(kt0 + vkey + 1) * 2048 + h * 64 + vd0];
  };
  auto writeKV = [&](int b) {
    *(u16x8*)&Ks[b][kr0 * 64 + swzc(kr0, kc0)] = kreg0;
    *(u16x8*)&Ks[b][(kr0 + 8) * 64 + swzc(kr0 + 8, kc0)] = kreg1;
#pragma unroll
    for (int d = 0; d < 8; ++d) {
      int row = vd0 + d;
      *(unsigned*)&Vs[b][row * 64 + swzc(row, vkey)] =
          (unsigned)vreg0[d] | ((unsigned)vreg1[d] << 16);
    }
  };

  loadKV(0);
  writeKV(0);
  __syncthreads();

  for (int t = 0; t < 64; ++t) {
    const int cur = t & 1;
    if (t < 63) loadKV((t + 1) * 64);

    const unsigned short* Kc = Ks[cur];
    const unsigned short* Vc = Vs[cur];

    f32x16 st[2];
    __builtin_amdgcn_s_setprio(1);
#pragma unroll
    for (int kb = 0; kb < 2; ++kb) {
      f32x16 a = {};
#pragma unroll
      for (int kt = 0; kt < 4; ++kt) {
        bf16x8 kf = *(const bf16x8*)&Kc[off[kb][kt]];
        a = __builtin_amdgcn_mfma_f32_32x32x16_bf16(kf, qf[kt], a, 0, 0, 0);
      }
      st[kb] = a;
    }
    __builtin_amdgcn_s_setprio(0);

    float t8[8];
#pragma unroll
    for (int j = 0; j < 8; ++j)
      t8[j] = fmaxf(F3(st[0][2 * j], st[0][2 * j + 1], st[1][2 * j]),
                    st[1][2 * j + 1]);
    float tmax = pair_max(F3(F3(t8[0], t8[1], t8[2]), F3(t8[3], t8[4], t8[5]),
                             fmaxf(t8[6], t8[7])));

    if (!__all(tmax <= m_r + 11.0f)) {
      float mn = fmaxf(m_r, tmax);
      float corr = __builtin_amdgcn_exp2f(m_r - mn);
      l_r *= corr;
#pragma unroll
      for (int dv = 0; dv < 2; ++dv)
#pragma unroll
        for (int r = 0; r < 16; ++r) oa[dv][r] *= corr;
      m_r = mn;
    }

    unsigned pk[16];
    float s0 = 0.f, s1 = 0.f, s2 = 0.f, s3 = 0.f;
#pragma unroll
    for (int kb = 0; kb < 2; ++kb)
#pragma unroll
      for (int j = 0; j < 8; ++j) {
        float pa = __builtin_amdgcn_exp2f(st[kb][2 * j] - m_r);
        float pb = __builtin_amdgcn_exp2f(st[kb][2 * j + 1] - m_r);
        if ((j & 3) == 0) s0 += pa + pb;
        else if ((j & 3) == 1) s1 += pa + pb;
        else if ((j & 3) == 2) s2 += pa + pb;
        else s3 += pa + pb;
        pk[kb * 8 + j] = cvtpk(pa, pb);
      }
    l_r += pair_sum(((s0 + s1) + (s2 + s3)));

    bf16x8 pfrag[4];
#pragma unroll
    for (int kt = 0; kt < 4; ++kt) {
      u32x2 sa = plswap(pk[4 * kt + 0], pk[4 * kt + 2]);
      u32x2 sb = plswap(pk[4 * kt + 1], pk[4 * kt + 3]);
      union { u32x4 u; bf16x8 b; } w;
      w.u.x = sa.x; w.u.y = sb.x; w.u.z = sa.y; w.u.w = sb.y;
      pfrag[kt] = w.b;
    }

    __builtin_amdgcn_s_setprio(1);
#pragma unroll
    for (int dv = 0; dv < 2; ++dv) {
#pragma unroll
      for (int kt = 0; kt < 4; ++kt) {
        bf16x8 vf = *(const bf16x8*)&Vc[off[dv][kt]];
        oa[dv] = __builtin_amdgcn_mfma_f32_32x32x16_bf16(vf, pfrag[kt], oa[dv], 0, 0, 0);
      }
    }
    __builtin_amdgcn_s_setprio(0);

    if (t < 63) {
      writeKV(cur ^ 1);
      __syncthreads();
    }
  }

  const float inv = 1.0f / l_r;
  const int qrow = q0 + wid * 32 + l31;
#pragma unroll
  for (int dv = 0; dv < 2; ++dv)
#pragma unroll
    for (int tq = 0; tq < 4; ++tq) {
      unsigned w0 = cvtpk(oa[dv][4 * tq + 0] * inv, oa[dv][4 * tq + 1] * inv);
      unsigned w1 = cvtpk(oa[dv][4 * tq + 2] * inv, oa[dv][4 * tq + 3] * inv);
      int dh = 32 * dv + 8 * tq + 4 * hi;
      u32x2 w2 = {w0, w1};
      *(u32x2*)&O[(size_t)qrow * 2048 + h * 64 + dh] = w2;
    }
}

// ---------- launch ----------
extern "C" void kernel_launch(void* const* d_in, const int* in_sizes, int n_in,
                              void* d_out, int out_size, void* d_ws, size_t ws_size,
                              hipStream_t stream) {
  const float* x  = (const float*)d_in[0];
  const float* Wq = (const float*)d_in[1];
  const float* bq = (const float*)d_in[2];
  const float* Wk = (const float*)d_in[3];
  const float* bk = (const float*)d_in[4];
  const float* Wv = (const float*)d_in[5];
  const float* bv = (const float*)d_in[6];
  const float* qn = (const float*)d_in[7];
  const float* kn = (const float*)d_in[8];
  const float* Wo = (const float*)d_in[9];
  const float* bo = (const float*)d_in[10];

  char* w = (char*)d_ws;
  unsigned short* Xbf = (unsigned short*)(w);                 // reused for O
  unsigned short* Wqb = (unsigned short*)(w + 16777216);
  unsigned short* Wkb = (unsigned short*)(w + 25165824);
  unsigned short* Wvb = (unsigned short*)(w + 33554432);
  unsigned short* Wob = (unsigned short*)(w + 41943040);
  unsigned short* Qb  = (unsigned short*)(w + 50331648);
  unsigned short* Kb  = (unsigned short*)(w + 67108864);
  unsigned short* Vb  = (unsigned short*)(w + 83886080);
  unsigned short* Ob  = Xbf;

  cast_bf16_kernel<<<1024, 256, 0, stream>>>(x, Xbf, 8388608 / 4);
  cast_w4_kernel<<<2048, 256, 0, stream>>>(Wq, Wk, Wv, Wo, Wqb, Wkb, Wvb, Wob);

  gemm8p<0><<<dim3(48, 32), 256, 65536, stream>>>(
      Xbf, Wqb, Wkb, Wvb, bq, bk, bv, Qb, Kb, Vb);

  rmsnorm2_kernel<<<8192, 256, 0, stream>>>(Qb, Kb, qn, kn);

  flash_attn<<<1024, 256, 0, stream>>>(Qb, Kb, Vb, Ob);

  gemm8p<1><<<dim3(16, 32), 256, 65536, stream>>>(
      Ob, Wob, Wob, Wob, bo, bo, bo, d_out, d_out, d_out);
}